// Round 3
// baseline (10968.439 us; speedup 1.0000x reference)
//
#include <hip/hip_runtime.h>
#include <hip/hip_bf16.h>

// STAttModel: B=16, T=12, N=1000, D=64, K=8 heads, d=8. All f32.
// Round 3: identical to round 2 except attn_fused_kernel compile fix
// (no arrays of pointers to __shared__ — use qkv[3][768] + ternary selects).
//   ws: A (1M), adpT (1M), T (12.288M), H1 (12.288M)  = 26,576,000 floats.

#define BT 192           // B*T
#define NN 1000
#define DD 64
#define BTN 192000       // B*T*N
#define ROWS_PER_BLK 64

struct Srcs { const float* p[2]; };
struct Wts  { const float* p[2]; };

__device__ __forceinline__ float gelu_f(float x) {
    return 0.5f * x * (1.0f + erff(x * 0.70710678118654752f));
}
__device__ __forceinline__ float sigmoid_f(float x) {
    return 1.0f / (1.0f + expf(-x));
}

// ---------------- adaptive adjacency: A[v,:] = softmax(mask(nv1@nv2)) ----------------
__global__ __launch_bounds__(256) void adp_softmax_kernel(
    const float* __restrict__ nv1,   // [1000,10]
    const float* __restrict__ nv2,   // [10,1000]
    const int*   __restrict__ adj,   // [1000,1000]
    float* __restrict__ A)           // [1000,1000]
{
    const int v = blockIdx.x;
    const int tid = threadIdx.x;
    __shared__ float n1[10];
    __shared__ float red[256];
    if (tid < 10) n1[tid] = nv1[v * 10 + tid];
    __syncthreads();

    float vals[4];
    float m = -3.0e38f;
    #pragma unroll
    for (int k = 0; k < 4; ++k) {
        int w = tid + k * 256;
        float val = -3.0e38f;
        if (w < NN) {
            if (adj[v * NN + w] > 0) {
                float s = 0.f;
                #pragma unroll
                for (int i = 0; i < 10; ++i) s = fmaf(n1[i], nv2[i * NN + w], s);
                val = s;
            } else {
                val = -9.0e15f;
            }
            m = fmaxf(m, val);
        }
        vals[k] = val;
    }
    red[tid] = m; __syncthreads();
    for (int s = 128; s > 0; s >>= 1) {
        if (tid < s) red[tid] = fmaxf(red[tid], red[tid + s]);
        __syncthreads();
    }
    m = red[0];
    __syncthreads();

    float e[4];
    float lsum = 0.f;
    #pragma unroll
    for (int k = 0; k < 4; ++k) {
        int w = tid + k * 256;
        e[k] = (w < NN) ? expf(vals[k] - m) : 0.f;
        lsum += e[k];
    }
    red[tid] = lsum; __syncthreads();
    for (int s = 128; s > 0; s >>= 1) {
        if (tid < s) red[tid] += red[tid + s];
        __syncthreads();
    }
    float inv = 1.0f / red[0];
    #pragma unroll
    for (int k = 0; k < 4; ++k) {
        int w = tid + k * 256;
        if (w < NN) A[v * NN + w] = e[k] * inv;
    }
}

// ---------------- 1000x1000 transpose ----------------
__global__ __launch_bounds__(256) void transpose_kernel(
    const float* __restrict__ in, float* __restrict__ ot)
{
    __shared__ float tile[32][33];
    const int tx = threadIdx.x & 31, ty = threadIdx.x >> 5;
    const int bx = blockIdx.x * 32, by = blockIdx.y * 32;
    #pragma unroll
    for (int k = 0; k < 4; ++k) {
        int y = by + ty + 8 * k, x = bx + tx;
        if (y < NN && x < NN) tile[ty + 8 * k][tx] = in[y * NN + x];
    }
    __syncthreads();
    #pragma unroll
    for (int k = 0; k < 4; ++k) {
        int y = bx + ty + 8 * k, x = by + tx;   // ot[y][x] = in[x][y]
        if (y < NN && x < NN) ot[y * NN + x] = tile[tx][ty + 8 * k];
    }
}

// ---------------- generic linear over chunked inputs ----------------
// out[row,:] = (ACCUM ? out[row,:] : 0) + sum_ch srcs[ch][row,:] @ wts[ch]
//              (+ bias if BIAS) -> (gelu if GELU) -> (+ xadd if ADDX)
template<bool ACCUM, bool BIAS, bool GELU, bool ADDX>
__global__ __launch_bounds__(256) void lin_kernel(
    Srcs srcs, Wts wts, int nchunks,
    const float* __restrict__ bias,  // [64] or null
    const float* __restrict__ xadd,  // [BTN,64] or null
    float* __restrict__ out)         // [BTN,64]
{
    const int tid = threadIdx.x;
    const int cg = tid & 15;
    const int rl = tid >> 4;
    const long rbase = (long)blockIdx.x * ROWS_PER_BLK;

    __shared__ float wt[64 * 64];
    __shared__ float rb[ROWS_PER_BLK * 68];   // padded stride 68

    float4 acc[4] = {};

    for (int ch = 0; ch < nchunks; ++ch) {
        __syncthreads();
        const float4* __restrict__ W4 = (const float4*)(wts.p[ch]);
        const float4* __restrict__ S4 = (const float4*)(srcs.p[ch] + rbase * 64);
        float4* wt4s = (float4*)wt;
        #pragma unroll
        for (int k = 0; k < 4; ++k) {
            int e = k * 256 + tid;            // 0..1023 float4s
            wt4s[e] = W4[e];
        }
        #pragma unroll
        for (int k = 0; k < 4; ++k) {
            int e = k * 256 + tid;            // 0..1023 float4s of 64x64
            int r = e >> 4, i4 = e & 15;
            float4 f = S4[e];
            *(float4*)&rb[r * 68 + i4 * 4] = f;
        }
        __syncthreads();
        const float4* wt4 = (const float4*)wt;
        #pragma unroll 4
        for (int i4 = 0; i4 < 16; ++i4) {
            float4 wv0 = wt4[(i4 * 4 + 0) * 16 + cg];
            float4 wv1 = wt4[(i4 * 4 + 1) * 16 + cg];
            float4 wv2 = wt4[(i4 * 4 + 2) * 16 + cg];
            float4 wv3 = wt4[(i4 * 4 + 3) * 16 + cg];
            #pragma unroll
            for (int j = 0; j < 4; ++j) {
                const float4 rv = *(const float4*)&rb[(rl + 16 * j) * 68 + i4 * 4];
                acc[j].x += rv.x * wv0.x + rv.y * wv1.x + rv.z * wv2.x + rv.w * wv3.x;
                acc[j].y += rv.x * wv0.y + rv.y * wv1.y + rv.z * wv2.y + rv.w * wv3.y;
                acc[j].z += rv.x * wv0.z + rv.y * wv1.z + rv.z * wv2.z + rv.w * wv3.z;
                acc[j].w += rv.x * wv0.w + rv.y * wv1.w + rv.z * wv2.w + rv.w * wv3.w;
            }
        }
    }

    float4 bv = make_float4(0.f, 0.f, 0.f, 0.f);
    if (BIAS) bv = *(const float4*)&bias[cg * 4];
    #pragma unroll
    for (int j = 0; j < 4; ++j) {
        long row = rbase + rl + 16 * j;
        float4 r = acc[j];
        if (ACCUM) {
            const float4 ov = *(const float4*)&out[row * 64 + cg * 4];
            r.x += ov.x; r.y += ov.y; r.z += ov.z; r.w += ov.w;
        }
        if (BIAS) { r.x += bv.x; r.y += bv.y; r.z += bv.z; r.w += bv.w; }
        if (GELU) {
            r.x = gelu_f(r.x); r.y = gelu_f(r.y); r.z = gelu_f(r.z); r.w = gelu_f(r.w);
        }
        if (ADDX) {
            const float4 xv = *(const float4*)&xadd[row * 64 + cg * 4];
            r.x += xv.x; r.y += xv.y; r.z += xv.z; r.w += xv.w;
        }
        *(float4*)&out[row * 64 + cg * 4] = r;
    }
}

// ---------------- graph aggregation: out[bt,v,:] = act(sum_w M[v,w] * H[bt,w,:]) ----------------
template<bool GELU>
__global__ __launch_bounds__(256) void agg_kernel(
    const float* __restrict__ M,     // [1000,1000]
    const float* __restrict__ H,     // [192,1000,64]
    float* __restrict__ out)         // [192,1000,64]
{
    const int tid = threadIdx.x;
    const int c = tid & 63;
    const int vl = tid >> 6;                 // 0..3
    const int bt = blockIdx.y;
    const int vbase = blockIdx.x * 32;

    __shared__ float hl[64 * 64];
    float acc[8] = {};

    const float4* __restrict__ H4 = (const float4*)(H + (long)bt * NN * DD);

    for (int wb = 0; wb < NN; wb += 64) {
        const int wcount = min(64, NN - wb);   // 64 or 40
        __syncthreads();
        float4* hl4 = (float4*)hl;
        #pragma unroll
        for (int k = 0; k < 4; ++k) {
            int e = k * 256 + tid;             // 0..1023
            int ww = e >> 4, c4 = e & 15;
            if (ww < wcount) hl4[e] = H4[(wb + ww) * 16 + c4];
        }
        __syncthreads();
        const int w4n = wcount >> 2;
        for (int w4 = 0; w4 < w4n; ++w4) {
            const float h0 = hl[(w4 * 4 + 0) * 64 + c];
            const float h1 = hl[(w4 * 4 + 1) * 64 + c];
            const float h2 = hl[(w4 * 4 + 2) * 64 + c];
            const float h3 = hl[(w4 * 4 + 3) * 64 + c];
            #pragma unroll
            for (int j = 0; j < 8; ++j) {
                int v = vbase + vl + 4 * j;
                v = v < NN ? v : NN - 1;       // clamp (store guarded below)
                const float4 a4 = *(const float4*)&M[(long)v * NN + wb + w4 * 4];
                acc[j] += a4.x * h0 + a4.y * h1 + a4.z * h2 + a4.w * h3;
            }
        }
    }

    #pragma unroll
    for (int j = 0; j < 8; ++j) {
        int v = vbase + vl + 4 * j;
        if (v < NN) {
            float x = acc[j];
            if (GELU) x = gelu_f(x);
            out[(long)bt * NN * DD + (long)v * DD + c] = x;
        }
    }
}

// ---------------- fused temporal causal attention, per (b,n) ----------------
// computes q/k/v = gelu([X,STE] @ w + b) in-kernel (weights staged in LDS),
// then causal softmax attention over T=12, writes merged heads [B,T,N,64].
__global__ __launch_bounds__(256) void attn_fused_kernel(
    const float* __restrict__ X, const float* __restrict__ STE,
    const float* __restrict__ w12, const float* __restrict__ b12,
    const float* __restrict__ w13, const float* __restrict__ b13,
    const float* __restrict__ w14, const float* __restrict__ b14,
    float* __restrict__ out)
{
    const int n = blockIdx.x;     // 0..999
    const int b = blockIdx.y;     // 0..15
    const int tid = threadIdx.x;  // 256

    __shared__ float xc[12 * 128];
    __shared__ float wlds[128 * 64];
    __shared__ float qkv[3][12 * 64];

    // stage xc[t][0:64]=X, [64:128]=STE for this (b, n)
    for (int e = tid; e < 12 * 128; e += 256) {
        int t = e >> 7, i = e & 127;
        long g = (((long)b * 12 + t) * NN + n) * 64 + (i & 63);
        xc[e] = (i < 64) ? X[g] : STE[g];
    }

    for (int m = 0; m < 3; ++m) {
        const float* wp = (m == 0) ? w12 : (m == 1) ? w13 : w14;
        const float* bb = (m == 0) ? b12 : (m == 1) ? b13 : b14;
        __syncthreads();   // prior compute done (and xc staged on first pass)
        const float4* W4 = (const float4*)wp;
        float4* wl4 = (float4*)wlds;
        #pragma unroll
        for (int k = 0; k < 8; ++k) wl4[k * 256 + tid] = W4[k * 256 + tid];
        __syncthreads();
        #pragma unroll
        for (int r = 0; r < 3; ++r) {
            int e = tid + r * 256;     // 0..767
            int t = e >> 6, c = e & 63;
            float dot = bb[c];
            #pragma unroll
            for (int i = 0; i < 128; ++i)
                dot = fmaf(xc[t * 128 + i], wlds[i * 64 + c], dot);
            qkv[m][t * 64 + c] = gelu_f(dot);
        }
    }
    __syncthreads();

    if (tid < 96) {
        const int h = tid / 12;   // 0..7
        const int t = tid % 12;   // 0..11
        const float scale = 0.35355339059327379f;  // 1/sqrt(8)
        float sc[12];
        float m = -3.0e38f;
        #pragma unroll
        for (int s = 0; s < 12; ++s) {
            float dot = 0.f;
            #pragma unroll
            for (int dd = 0; dd < 8; ++dd)
                dot += qkv[0][t * 64 + h * 8 + dd] * qkv[1][s * 64 + h * 8 + dd];
            sc[s] = (s <= t) ? dot * scale : -3.0e38f;
            m = fmaxf(m, sc[s]);
        }
        float sum = 0.f;
        #pragma unroll
        for (int s = 0; s < 12; ++s) {
            float e = (s <= t) ? expf(sc[s] - m) : 0.f;
            sc[s] = e;
            sum += e;
        }
        const float inv = 1.0f / sum;
        float o[8] = {};
        #pragma unroll
        for (int s = 0; s < 12; ++s) {
            float p = sc[s] * inv;
            #pragma unroll
            for (int dd = 0; dd < 8; ++dd)
                o[dd] += p * qkv[2][s * 64 + h * 8 + dd];
        }
        long gout = (((long)b * 12 + t) * NN + n) * 64 + h * 8;
        #pragma unroll
        for (int dd = 0; dd < 8; ++dd) out[gout + dd] = o[dd];
    }
}

// ---------------- fused gated fusion front half ----------------
// z = sigmoid(hs@w17 + ht@w18 + b17 + b18); h = z*hs + (1-z)*ht
__global__ __launch_bounds__(256) void zfuse_kernel(
    const float* __restrict__ hs, const float* __restrict__ ht,
    const float* __restrict__ w17, const float* __restrict__ b17,
    const float* __restrict__ w18, const float* __restrict__ b18,
    float* __restrict__ out)
{
    const int tid = threadIdx.x;
    const int cg = tid & 15;
    const int rl = tid >> 4;
    const long rbase = (long)blockIdx.x * ROWS_PER_BLK;

    __shared__ float wt[64 * 64];
    __shared__ float rb[ROWS_PER_BLK * 68];

    float4 acc[4] = {};

    for (int ch = 0; ch < 2; ++ch) {
        const float* sp = (ch == 0) ? hs : ht;
        const float* wp = (ch == 0) ? w17 : w18;
        __syncthreads();
        const float4* W4 = (const float4*)wp;
        const float4* S4 = (const float4*)(sp + rbase * 64);
        float4* wt4s = (float4*)wt;
        #pragma unroll
        for (int k = 0; k < 4; ++k) {
            int e = k * 256 + tid;
            wt4s[e] = W4[e];
        }
        #pragma unroll
        for (int k = 0; k < 4; ++k) {
            int e = k * 256 + tid;
            int r = e >> 4, i4 = e & 15;
            float4 f = S4[e];
            *(float4*)&rb[r * 68 + i4 * 4] = f;
        }
        __syncthreads();
        const float4* wt4 = (const float4*)wt;
        #pragma unroll 4
        for (int i4 = 0; i4 < 16; ++i4) {
            float4 wv0 = wt4[(i4 * 4 + 0) * 16 + cg];
            float4 wv1 = wt4[(i4 * 4 + 1) * 16 + cg];
            float4 wv2 = wt4[(i4 * 4 + 2) * 16 + cg];
            float4 wv3 = wt4[(i4 * 4 + 3) * 16 + cg];
            #pragma unroll
            for (int j = 0; j < 4; ++j) {
                const float4 rv = *(const float4*)&rb[(rl + 16 * j) * 68 + i4 * 4];
                acc[j].x += rv.x * wv0.x + rv.y * wv1.x + rv.z * wv2.x + rv.w * wv3.x;
                acc[j].y += rv.x * wv0.y + rv.y * wv1.y + rv.z * wv2.y + rv.w * wv3.y;
                acc[j].z += rv.x * wv0.z + rv.y * wv1.z + rv.z * wv2.z + rv.w * wv3.z;
                acc[j].w += rv.x * wv0.w + rv.y * wv1.w + rv.z * wv2.w + rv.w * wv3.w;
            }
        }
    }

    const float4 b1 = *(const float4*)&b17[cg * 4];
    const float4 b2 = *(const float4*)&b18[cg * 4];
    #pragma unroll
    for (int j = 0; j < 4; ++j) {
        long row = rbase + rl + 16 * j;
        const float4 h1 = *(const float4*)&hs[row * 64 + cg * 4];
        const float4 h2 = *(const float4*)&ht[row * 64 + cg * 4];
        float4 r;
        float z;
        z = sigmoid_f(acc[j].x + b1.x + b2.x); r.x = z * h1.x + (1.f - z) * h2.x;
        z = sigmoid_f(acc[j].y + b1.y + b2.y); r.y = z * h1.y + (1.f - z) * h2.y;
        z = sigmoid_f(acc[j].z + b1.z + b2.z); r.z = z * h1.z + (1.f - z) * h2.z;
        z = sigmoid_f(acc[j].w + b1.w + b2.w); r.w = z * h1.w + (1.f - z) * h2.w;
        *(float4*)&out[row * 64 + cg * 4] = r;
    }
}

extern "C" void kernel_launch(void* const* d_in, const int* in_sizes, int n_in,
                              void* d_out, int out_size, void* d_ws, size_t ws_size,
                              hipStream_t stream) {
    const float* X    = (const float*)d_in[0];
    const float* STE  = (const float*)d_in[1];
    const float* adp  = (const float*)d_in[2];
    const int*   adj0 = (const int*)d_in[3];
    const int*   adj1 = (const int*)d_in[4];
    const float* w30  = (const float*)d_in[5];
    const float* b30  = (const float*)d_in[6];
    const float* wg   = (const float*)d_in[7];
    const float* bg   = (const float*)d_in[8];
    const float* wg1  = (const float*)d_in[9];   const float* bg1 = (const float*)d_in[10];
    const float* nv1_1= (const float*)d_in[11];  const float* nv2_1 = (const float*)d_in[12];
    const float* wg2  = (const float*)d_in[13];  const float* bg2 = (const float*)d_in[14];
    const float* nv1_2= (const float*)d_in[15];  const float* nv2_2 = (const float*)d_in[16];
    const float* wg3  = (const float*)d_in[17];  const float* bg3 = (const float*)d_in[18];
    const float* nv1_3= (const float*)d_in[19];  const float* nv2_3 = (const float*)d_in[20];
    const float* wg4  = (const float*)d_in[21];  const float* bg4 = (const float*)d_in[22];
    const float* nv1_4= (const float*)d_in[23];  const float* nv2_4 = (const float*)d_in[24];
    const float* w12  = (const float*)d_in[25];  const float* b12 = (const float*)d_in[26];
    const float* w13  = (const float*)d_in[27];  const float* b13 = (const float*)d_in[28];
    const float* w14  = (const float*)d_in[29];  const float* b14 = (const float*)d_in[30];
    const float* w15  = (const float*)d_in[31];  const float* b15 = (const float*)d_in[32];
    const float* w16  = (const float*)d_in[33];  const float* b16 = (const float*)d_in[34];
    const float* w17  = (const float*)d_in[35];  const float* b17 = (const float*)d_in[36];
    const float* w18  = (const float*)d_in[37];  const float* b18 = (const float*)d_in[38];
    const float* w19  = (const float*)d_in[39];  const float* b19 = (const float*)d_in[40];
    const float* w20  = (const float*)d_in[41];  const float* b20 = (const float*)d_in[42];

    // workspace: A (1M), adpT (1M), T (12.288M), H1 (12.288M) floats
    const size_t need = (size_t)(1000000 + 1000000 + 12288000 + 12288000) * 4;
    if (ws_size < need) return;   // diagnostic: leaves d_out poisoned

    float* ws = (float*)d_ws;
    float* A    = ws;
    float* adpT = A + 1000000;
    float* T    = adpT + 1000000;
    float* H1   = T + 12288000;
    float* OUT  = (float*)d_out;   // doubles as HS accumulator

    const dim3 aggGrid(32, BT);
    const int linGrid = BTN / ROWS_PER_BLK;   // 3000

    Srcs s{}; Wts w{};
    const int WCH = 64 * 64;

    transpose_kernel<<<dim3(32, 32), 256, 0, stream>>>(adp, adpT);

    // ---- HS accumulator init: OUT = X @ w30[0:64] (no bias yet) ----
    s.p[0] = X; w.p[0] = w30;
    lin_kernel<false, false, false, false><<<linGrid, 256, 0, stream>>>(s, w, 1, nullptr, nullptr, OUT);

    // ---- gat1: HS1 = gelu(A1 @ gelu([X,STE]@wg1+bg1)) ----
    adp_softmax_kernel<<<NN, 256, 0, stream>>>(nv1_1, nv2_1, adj0, A);
    s.p[0] = X; s.p[1] = STE; w.p[0] = wg1; w.p[1] = wg1 + WCH;
    lin_kernel<false, true, true, false><<<linGrid, 256, 0, stream>>>(s, w, 2, bg1, nullptr, T);
    agg_kernel<true><<<aggGrid, 256, 0, stream>>>(A, T, H1);
    s.p[0] = H1; w.p[0] = w30 + 1 * WCH;
    lin_kernel<true, false, false, false><<<linGrid, 256, 0, stream>>>(s, w, 1, nullptr, nullptr, OUT);

    // ---- gat2: HS2 = gelu(A2 @ gelu([HS1,STE]@wg2+bg2)) ----
    s.p[0] = H1; s.p[1] = STE; w.p[0] = wg2; w.p[1] = wg2 + WCH;
    lin_kernel<false, true, true, false><<<linGrid, 256, 0, stream>>>(s, w, 2, bg2, nullptr, T);
    adp_softmax_kernel<<<NN, 256, 0, stream>>>(nv1_2, nv2_2, adj0, A);
    agg_kernel<true><<<aggGrid, 256, 0, stream>>>(A, T, H1);
    s.p[0] = H1; w.p[0] = w30 + 2 * WCH;
    lin_kernel<true, false, false, false><<<linGrid, 256, 0, stream>>>(s, w, 1, nullptr, nullptr, OUT);

    // ---- gat3 ----
    adp_softmax_kernel<<<NN, 256, 0, stream>>>(nv1_3, nv2_3, adj1, A);
    s.p[0] = X; s.p[1] = STE; w.p[0] = wg3; w.p[1] = wg3 + WCH;
    lin_kernel<false, true, true, false><<<linGrid, 256, 0, stream>>>(s, w, 2, bg3, nullptr, T);
    agg_kernel<true><<<aggGrid, 256, 0, stream>>>(A, T, H1);
    s.p[0] = H1; w.p[0] = w30 + 3 * WCH;
    lin_kernel<true, false, false, false><<<linGrid, 256, 0, stream>>>(s, w, 1, nullptr, nullptr, OUT);

    // ---- gat4 ----
    s.p[0] = H1; s.p[1] = STE; w.p[0] = wg4; w.p[1] = wg4 + WCH;
    lin_kernel<false, true, true, false><<<linGrid, 256, 0, stream>>>(s, w, 2, bg4, nullptr, T);
    adp_softmax_kernel<<<NN, 256, 0, stream>>>(nv1_4, nv2_4, adj1, A);
    agg_kernel<true><<<aggGrid, 256, 0, stream>>>(A, T, H1);
    s.p[0] = H1; w.p[0] = w30 + 4 * WCH;
    lin_kernel<true, false, false, false><<<linGrid, 256, 0, stream>>>(s, w, 1, nullptr, nullptr, OUT);

    // ---- gcn5: HS5 = adpT-agg(gelu([X,STE]@wg+bg)), no outer gelu ----
    s.p[0] = X; s.p[1] = STE; w.p[0] = wg; w.p[1] = wg + WCH;
    lin_kernel<false, true, true, false><<<linGrid, 256, 0, stream>>>(s, w, 2, bg, nullptr, T);
    agg_kernel<false><<<aggGrid, 256, 0, stream>>>(adpT, T, H1);
    s.p[0] = H1; w.p[0] = w30 + 5 * WCH;
    lin_kernel<true, false, false, false><<<linGrid, 256, 0, stream>>>(s, w, 1, nullptr, nullptr, OUT);

    // ---- gcn6 + finalize HS = gelu(acc + b30) ----
    s.p[0] = H1; s.p[1] = STE; w.p[0] = wg; w.p[1] = wg + WCH;
    lin_kernel<false, true, true, false><<<linGrid, 256, 0, stream>>>(s, w, 2, bg, nullptr, T);
    agg_kernel<false><<<aggGrid, 256, 0, stream>>>(adpT, T, H1);
    s.p[0] = H1; w.p[0] = w30 + 6 * WCH;
    lin_kernel<true, true, true, false><<<linGrid, 256, 0, stream>>>(s, w, 1, b30, nullptr, OUT); // OUT = HS

    // ---- temporal attention ----
    attn_fused_kernel<<<dim3(NN, 16), 256, 0, stream>>>(X, STE, w12, b12, w13, b13, w14, b14, T);
    s.p[0] = T; w.p[0] = w15;
    lin_kernel<false, true, true, false><<<linGrid, 256, 0, stream>>>(s, w, 1, b15, nullptr, H1);
    s.p[0] = H1; w.p[0] = w16;
    lin_kernel<false, true, false, false><<<linGrid, 256, 0, stream>>>(s, w, 1, b16, nullptr, T); // T = HT

    // ---- gated fusion ----
    zfuse_kernel<<<linGrid, 256, 0, stream>>>(OUT, T, w17, b17, w18, b18, H1);   // H1 = h
    s.p[0] = H1; w.p[0] = w19;
    lin_kernel<false, true, true, false><<<linGrid, 256, 0, stream>>>(s, w, 1, b19, nullptr, T);
    s.p[0] = T; w.p[0] = w20;
    lin_kernel<false, true, false, true><<<linGrid, 256, 0, stream>>>(s, w, 1, b20, X, OUT); // X + lin
}

// Round 5
// 2331.308 us; speedup vs baseline: 4.7048x; 4.7048x over previous
//
#include <hip/hip_runtime.h>
#include <hip/hip_bf16.h>

// STAttModel: B=16, T=12, N=1000, D=64. Round 5: MFMA aggregation with
// split-precision (hi+lo bf16) on the GCN path.
//   - GAT aggs (4): plain bf16 MFMA (A=softmax, H=O(1) -> error ~1e-2)
//   - GCN aggs (2): A,H split hi+lo bf16; 3-term MFMA (rel err ~5e-5)
// ws layout (105.55 MB total):
//   P [0, 50,331,648):        Hpk_hi (25.17M) + Hpk_lo (25.17M)  |  T f32 (attn phase)
//   Q [P, P+49,152,000):      H1 f32
//   S [P+Q, +6,064,384):      gat: A f32 (4MB) + Apk (2.06MB)
//                             gcn: ApkT_hi + ApkT_lo (4.13MB, packed after gat4)

#define BT 192
#define NN 1000
#define DD 64
#define BTN 192000
#define ROWS_PER_BLK 64
#define HPK_ELEMS 12582912L   // ushorts per Hpk plane (192*32*2048)
#define APK_ELEMS 1032192L    // ushorts per Apk plane (63*32*512)

typedef unsigned short ushort_t;
typedef __attribute__((ext_vector_type(8))) __bf16 bf16x8;
typedef __attribute__((ext_vector_type(4))) float f32x4;

struct Srcs { const float* p[2]; };
struct Wts  { const float* p[2]; };

__device__ __forceinline__ float gelu_f(float x) {
    return 0.5f * x * (1.0f + erff(x * 0.70710678118654752f));
}
__device__ __forceinline__ float sigmoid_f(float x) {
    return 1.0f / (1.0f + expf(-x));
}
__device__ __forceinline__ ushort_t f2bf(float f) {
    unsigned u = __float_as_uint(f);
    unsigned r = (u + 0x7FFFu + ((u >> 16) & 1u)) >> 16;
    return (ushort_t)r;
}
__device__ __forceinline__ float bf2f(ushort_t h) {
    return __uint_as_float(((unsigned)h) << 16);
}

// ---------------- adaptive adjacency: A[v,:] = softmax(mask(nv1@nv2)) ----------------
__global__ __launch_bounds__(256) void adp_softmax_kernel(
    const float* __restrict__ nv1, const float* __restrict__ nv2,
    const int* __restrict__ adj, float* __restrict__ A)
{
    const int v = blockIdx.x;
    const int tid = threadIdx.x;
    __shared__ float n1[10];
    __shared__ float red[256];
    if (tid < 10) n1[tid] = nv1[v * 10 + tid];
    __syncthreads();

    float vals[4];
    float m = -3.0e38f;
    #pragma unroll
    for (int k = 0; k < 4; ++k) {
        int w = tid + k * 256;
        float val = -3.0e38f;
        if (w < NN) {
            if (adj[v * NN + w] > 0) {
                float s = 0.f;
                #pragma unroll
                for (int i = 0; i < 10; ++i) s = fmaf(n1[i], nv2[i * NN + w], s);
                val = s;
            } else {
                val = -9.0e15f;
            }
            m = fmaxf(m, val);
        }
        vals[k] = val;
    }
    red[tid] = m; __syncthreads();
    for (int s = 128; s > 0; s >>= 1) {
        if (tid < s) red[tid] = fmaxf(red[tid], red[tid + s]);
        __syncthreads();
    }
    m = red[0];
    __syncthreads();

    float e[4];
    float lsum = 0.f;
    #pragma unroll
    for (int k = 0; k < 4; ++k) {
        int w = tid + k * 256;
        e[k] = (w < NN) ? expf(vals[k] - m) : 0.f;
        lsum += e[k];
    }
    red[tid] = lsum; __syncthreads();
    for (int s = 128; s > 0; s >>= 1) {
        if (tid < s) red[tid] += red[tid + s];
        __syncthreads();
    }
    float inv = 1.0f / red[0];
    #pragma unroll
    for (int k = 0; k < 4; ++k) {
        int w = tid + k * 256;
        if (w < NN) A[v * NN + w] = e[k] * inv;
    }
}

// ---------------- pack adjacency f32 -> bf16 MFMA A-frag layout ----------------
// pk[v16][kb][lane][j] = M[v16*16 + (l&15)][kb*32 + (l>>4)*8 + j]  (0-padded)
// TRANS reads M^T; SPLIT also writes the bf16 residual to pklo.
template<bool TRANS, bool SPLIT>
__global__ __launch_bounds__(256) void pack_adj_kernel(
    const float* __restrict__ M, ushort_t* __restrict__ pk, ushort_t* __restrict__ pklo)
{
    const int g = blockIdx.x * 256 + threadIdx.x;   // < 63*32*64
    if (g >= 63 * 32 * 64) return;
    const int l = g & 63;
    const int kb = (g >> 6) & 31;
    const int v16 = g >> 11;
    const int row = v16 * 16 + (l & 15);
    const int k0 = kb * 32 + (l >> 4) * 8;
    union { ushort_t u[8]; uint4 v; } o, olo;
    #pragma unroll
    for (int j = 0; j < 8; ++j) {
        int k = k0 + j;
        float val = 0.f;
        if (row < NN && k < NN)
            val = TRANS ? M[(long)k * NN + row] : M[(long)row * NN + k];
        ushort_t h = f2bf(val);
        o.u[j] = h;
        if (SPLIT) olo.u[j] = f2bf(val - bf2f(h));
    }
    *(uint4*)(pk + (long)g * 8) = o.v;
    if (SPLIT) *(uint4*)(pklo + (long)g * 8) = olo.v;
}

// ---------------- generic linear over chunked inputs ----------------
// out = (ACCUM? out:0) + sum_ch srcs[ch] @ wts[ch] (+bias) -> (gelu) -> (+X)
// PACK=1: bf16 B-frag layout to (ushort*)out. PACK=2: also residual plane at +HPK_ELEMS.
template<bool ACCUM, bool BIAS, bool GELU, bool ADDX, int PACK>
__global__ __launch_bounds__(256) void lin_kernel(
    Srcs srcs, Wts wts, int nchunks,
    const float* __restrict__ bias,
    const float* __restrict__ xadd,
    float* __restrict__ out)
{
    const int tid = threadIdx.x;
    const int cg = tid & 15;
    const int rl = tid >> 4;
    const long rbase = (long)blockIdx.x * ROWS_PER_BLK;

    __shared__ float wt[64 * 64];
    __shared__ float rb[ROWS_PER_BLK * 68];

    float4 acc[4] = {};

    for (int ch = 0; ch < nchunks; ++ch) {
        __syncthreads();
        const float4* __restrict__ W4 = (const float4*)(wts.p[ch]);
        const float4* __restrict__ S4 = (const float4*)(srcs.p[ch] + rbase * 64);
        float4* wt4s = (float4*)wt;
        #pragma unroll
        for (int k = 0; k < 4; ++k) {
            int e = k * 256 + tid;
            wt4s[e] = W4[e];
        }
        #pragma unroll
        for (int k = 0; k < 4; ++k) {
            int e = k * 256 + tid;
            int r = e >> 4, i4 = e & 15;
            float4 f = S4[e];
            *(float4*)&rb[r * 68 + i4 * 4] = f;
        }
        __syncthreads();
        const float4* wt4 = (const float4*)wt;
        #pragma unroll 4
        for (int i4 = 0; i4 < 16; ++i4) {
            float4 wv0 = wt4[(i4 * 4 + 0) * 16 + cg];
            float4 wv1 = wt4[(i4 * 4 + 1) * 16 + cg];
            float4 wv2 = wt4[(i4 * 4 + 2) * 16 + cg];
            float4 wv3 = wt4[(i4 * 4 + 3) * 16 + cg];
            #pragma unroll
            for (int j = 0; j < 4; ++j) {
                const float4 rv = *(const float4*)&rb[(rl + 16 * j) * 68 + i4 * 4];
                acc[j].x += rv.x * wv0.x + rv.y * wv1.x + rv.z * wv2.x + rv.w * wv3.x;
                acc[j].y += rv.x * wv0.y + rv.y * wv1.y + rv.z * wv2.y + rv.w * wv3.y;
                acc[j].z += rv.x * wv0.z + rv.y * wv1.z + rv.z * wv2.z + rv.w * wv3.z;
                acc[j].w += rv.x * wv0.w + rv.y * wv1.w + rv.z * wv2.w + rv.w * wv3.w;
            }
        }
    }

    float4 bv = make_float4(0.f, 0.f, 0.f, 0.f);
    if (BIAS) bv = *(const float4*)&bias[cg * 4];
    #pragma unroll
    for (int j = 0; j < 4; ++j) {
        long row = rbase + rl + 16 * j;
        float4 r = acc[j];
        if (ACCUM) {
            const float4 ov = *(const float4*)&out[row * 64 + cg * 4];
            r.x += ov.x; r.y += ov.y; r.z += ov.z; r.w += ov.w;
        }
        if (BIAS) { r.x += bv.x; r.y += bv.y; r.z += bv.z; r.w += bv.w; }
        if (GELU) {
            r.x = gelu_f(r.x); r.y = gelu_f(r.y); r.z = gelu_f(r.z); r.w = gelu_f(r.w);
        }
        if (ADDX) {
            const float4 xv = *(const float4*)&xadd[row * 64 + cg * 4];
            r.x += xv.x; r.y += xv.y; r.z += xv.z; r.w += xv.w;
        }
        if (PACK) {
            ushort_t* o16 = (ushort_t*)out;
            int bt = (int)(row / 1000);
            int n = (int)(row - (long)bt * 1000);
            int kb = n >> 5, kr = n & 31;
            long base = (long)bt * 65536 + kb * 2048 + (kr >> 3) * 128 + (kr & 7);
            float vv[4] = { r.x, r.y, r.z, r.w };
            #pragma unroll
            for (int cc = 0; cc < 4; ++cc) {
                int c = cg * 4 + cc;
                long idx = base + (c >> 4) * 512 + (c & 15) * 8;
                ushort_t h = f2bf(vv[cc]);
                o16[idx] = h;
                if (PACK == 2) o16[HPK_ELEMS + idx] = f2bf(vv[cc] - bf2f(h));
            }
        } else {
            *(float4*)&out[row * 64 + cg * 4] = r;
        }
    }
}

// ---------------- MFMA graph aggregation ----------------
// out[bt,v,:] = act(sum_w M[v,w] * H[bt,w,:]); M A-frag pack, H B-frag pack.
// SPLIT: A,H have residual planes at +APK_ELEMS / +HPK_ELEMS; 3-term product.
template<bool GELU, bool SPLIT>
__global__ __launch_bounds__(256) void agg_mfma_kernel(
    const ushort_t* __restrict__ Apk,   // [63][32][512] (+lo plane)
    const ushort_t* __restrict__ Hpk,   // [192][32][4][512] (+lo plane)
    float* __restrict__ out)            // [192,1000,64]
{
    const int tid = threadIdx.x;
    const int wave = tid >> 6, l = tid & 63;
    const int wrow = blockIdx.x * 64 + wave * 16;
    if (wrow >= NN) return;
    const int v16 = wrow >> 4;
    const int bt = blockIdx.y;

    const bf16x8* __restrict__ Ab  = (const bf16x8*)(Apk + (long)v16 * 16384);
    const bf16x8* __restrict__ Abl = (const bf16x8*)(Apk + APK_ELEMS + (long)v16 * 16384);
    const bf16x8* __restrict__ Hb  = (const bf16x8*)(Hpk + (long)bt * 65536);
    const bf16x8* __restrict__ Hbl = (const bf16x8*)(Hpk + HPK_ELEMS + (long)bt * 65536);

    f32x4 acc0 = {0.f, 0.f, 0.f, 0.f};
    f32x4 acc1 = acc0, acc2 = acc0, acc3 = acc0;

    #pragma unroll 2
    for (int kb = 0; kb < 32; ++kb) {
        bf16x8 a  = Ab[kb * 64 + l];
        bf16x8 b0 = Hb[kb * 256 + l];
        bf16x8 b1 = Hb[kb * 256 + 64 + l];
        bf16x8 b2 = Hb[kb * 256 + 128 + l];
        bf16x8 b3 = Hb[kb * 256 + 192 + l];
        acc0 = __builtin_amdgcn_mfma_f32_16x16x32_bf16(a, b0, acc0, 0, 0, 0);
        acc1 = __builtin_amdgcn_mfma_f32_16x16x32_bf16(a, b1, acc1, 0, 0, 0);
        acc2 = __builtin_amdgcn_mfma_f32_16x16x32_bf16(a, b2, acc2, 0, 0, 0);
        acc3 = __builtin_amdgcn_mfma_f32_16x16x32_bf16(a, b3, acc3, 0, 0, 0);
        if (SPLIT) {
            bf16x8 al  = Abl[kb * 64 + l];
            bf16x8 c0 = Hbl[kb * 256 + l];
            bf16x8 c1 = Hbl[kb * 256 + 64 + l];
            bf16x8 c2 = Hbl[kb * 256 + 128 + l];
            bf16x8 c3 = Hbl[kb * 256 + 192 + l];
            acc0 = __builtin_amdgcn_mfma_f32_16x16x32_bf16(a, c0, acc0, 0, 0, 0);
            acc1 = __builtin_amdgcn_mfma_f32_16x16x32_bf16(a, c1, acc1, 0, 0, 0);
            acc2 = __builtin_amdgcn_mfma_f32_16x16x32_bf16(a, c2, acc2, 0, 0, 0);
            acc3 = __builtin_amdgcn_mfma_f32_16x16x32_bf16(a, c3, acc3, 0, 0, 0);
            acc0 = __builtin_amdgcn_mfma_f32_16x16x32_bf16(al, b0, acc0, 0, 0, 0);
            acc1 = __builtin_amdgcn_mfma_f32_16x16x32_bf16(al, b1, acc1, 0, 0, 0);
            acc2 = __builtin_amdgcn_mfma_f32_16x16x32_bf16(al, b2, acc2, 0, 0, 0);
            acc3 = __builtin_amdgcn_mfma_f32_16x16x32_bf16(al, b3, acc3, 0, 0, 0);
        }
    }

    const int r0 = wrow + (l >> 4) * 4;
    const int col = l & 15;
    float* ob = out + (long)bt * NN * DD;
    #pragma unroll
    for (int i = 0; i < 4; ++i) {
        int v = r0 + i;
        if (v < NN) {
            float x0 = acc0[i], x1 = acc1[i], x2 = acc2[i], x3 = acc3[i];
            if (GELU) { x0 = gelu_f(x0); x1 = gelu_f(x1); x2 = gelu_f(x2); x3 = gelu_f(x3); }
            ob[(long)v * DD + col]      = x0;
            ob[(long)v * DD + 16 + col] = x1;
            ob[(long)v * DD + 32 + col] = x2;
            ob[(long)v * DD + 48 + col] = x3;
        }
    }
}

// ---------------- fused temporal causal attention, per (b,n) ----------------
__global__ __launch_bounds__(256) void attn_fused_kernel(
    const float* __restrict__ X, const float* __restrict__ STE,
    const float* __restrict__ w12, const float* __restrict__ b12,
    const float* __restrict__ w13, const float* __restrict__ b13,
    const float* __restrict__ w14, const float* __restrict__ b14,
    float* __restrict__ out)
{
    const int n = blockIdx.x;
    const int b = blockIdx.y;
    const int tid = threadIdx.x;

    __shared__ float xc[12 * 128];
    __shared__ float wlds[128 * 64];
    __shared__ float qkv[3][12 * 64];

    for (int e = tid; e < 12 * 128; e += 256) {
        int t = e >> 7, i = e & 127;
        long g = (((long)b * 12 + t) * NN + n) * 64 + (i & 63);
        xc[e] = (i < 64) ? X[g] : STE[g];
    }

    for (int m = 0; m < 3; ++m) {
        const float* wp = (m == 0) ? w12 : (m == 1) ? w13 : w14;
        const float* bb = (m == 0) ? b12 : (m == 1) ? b13 : b14;
        __syncthreads();
        const float4* W4 = (const float4*)wp;
        float4* wl4 = (float4*)wlds;
        #pragma unroll
        for (int k = 0; k < 8; ++k) wl4[k * 256 + tid] = W4[k * 256 + tid];
        __syncthreads();
        #pragma unroll
        for (int r = 0; r < 3; ++r) {
            int e = tid + r * 256;
            int t = e >> 6, c = e & 63;
            float dot = bb[c];
            #pragma unroll
            for (int i = 0; i < 128; ++i)
                dot = fmaf(xc[t * 128 + i], wlds[i * 64 + c], dot);
            qkv[m][t * 64 + c] = gelu_f(dot);
        }
    }
    __syncthreads();

    if (tid < 96) {
        const int h = tid / 12;
        const int t = tid % 12;
        const float scale = 0.35355339059327379f;
        float sc[12];
        float m = -3.0e38f;
        #pragma unroll
        for (int s = 0; s < 12; ++s) {
            float dot = 0.f;
            #pragma unroll
            for (int dd = 0; dd < 8; ++dd)
                dot += qkv[0][t * 64 + h * 8 + dd] * qkv[1][s * 64 + h * 8 + dd];
            sc[s] = (s <= t) ? dot * scale : -3.0e38f;
            m = fmaxf(m, sc[s]);
        }
        float sum = 0.f;
        #pragma unroll
        for (int s = 0; s < 12; ++s) {
            float e = (s <= t) ? expf(sc[s] - m) : 0.f;
            sc[s] = e;
            sum += e;
        }
        const float inv = 1.0f / sum;
        float o[8] = {};
        #pragma unroll
        for (int s = 0; s < 12; ++s) {
            float p = sc[s] * inv;
            #pragma unroll
            for (int dd = 0; dd < 8; ++dd)
                o[dd] += p * qkv[2][s * 64 + h * 8 + dd];
        }
        long gout = (((long)b * 12 + t) * NN + n) * 64 + h * 8;
        #pragma unroll
        for (int dd = 0; dd < 8; ++dd) out[gout + dd] = o[dd];
    }
}

// ---------------- gated fusion: z = sig(hs@w17 + ht@w18 + b); h = z*hs+(1-z)*ht ----
__global__ __launch_bounds__(256) void zfuse_kernel(
    const float* __restrict__ hs, const float* __restrict__ ht,
    const float* __restrict__ w17, const float* __restrict__ b17,
    const float* __restrict__ w18, const float* __restrict__ b18,
    float* __restrict__ out)
{
    const int tid = threadIdx.x;
    const int cg = tid & 15;
    const int rl = tid >> 4;
    const long rbase = (long)blockIdx.x * ROWS_PER_BLK;

    __shared__ float wt[64 * 64];
    __shared__ float rb[ROWS_PER_BLK * 68];

    float4 acc[4] = {};

    for (int ch = 0; ch < 2; ++ch) {
        const float* sp = (ch == 0) ? hs : ht;
        const float* wp = (ch == 0) ? w17 : w18;
        __syncthreads();
        const float4* W4 = (const float4*)wp;
        const float4* S4 = (const float4*)(sp + rbase * 64);
        float4* wt4s = (float4*)wt;
        #pragma unroll
        for (int k = 0; k < 4; ++k) {
            int e = k * 256 + tid;
            wt4s[e] = W4[e];
        }
        #pragma unroll
        for (int k = 0; k < 4; ++k) {
            int e = k * 256 + tid;
            int r = e >> 4, i4 = e & 15;
            float4 f = S4[e];
            *(float4*)&rb[r * 68 + i4 * 4] = f;
        }
        __syncthreads();
        const float4* wt4 = (const float4*)wt;
        #pragma unroll 4
        for (int i4 = 0; i4 < 16; ++i4) {
            float4 wv0 = wt4[(i4 * 4 + 0) * 16 + cg];
            float4 wv1 = wt4[(i4 * 4 + 1) * 16 + cg];
            float4 wv2 = wt4[(i4 * 4 + 2) * 16 + cg];
            float4 wv3 = wt4[(i4 * 4 + 3) * 16 + cg];
            #pragma unroll
            for (int j = 0; j < 4; ++j) {
                const float4 rv = *(const float4*)&rb[(rl + 16 * j) * 68 + i4 * 4];
                acc[j].x += rv.x * wv0.x + rv.y * wv1.x + rv.z * wv2.x + rv.w * wv3.x;
                acc[j].y += rv.x * wv0.y + rv.y * wv1.y + rv.z * wv2.y + rv.w * wv3.y;
                acc[j].z += rv.x * wv0.z + rv.y * wv1.z + rv.z * wv2.z + rv.w * wv3.z;
                acc[j].w += rv.x * wv0.w + rv.y * wv1.w + rv.z * wv2.w + rv.w * wv3.w;
            }
        }
    }

    const float4 b1 = *(const float4*)&b17[cg * 4];
    const float4 b2 = *(const float4*)&b18[cg * 4];
    #pragma unroll
    for (int j = 0; j < 4; ++j) {
        long row = rbase + rl + 16 * j;
        const float4 h1 = *(const float4*)&hs[row * 64 + cg * 4];
        const float4 h2 = *(const float4*)&ht[row * 64 + cg * 4];
        float4 r;
        float z;
        z = sigmoid_f(acc[j].x + b1.x + b2.x); r.x = z * h1.x + (1.f - z) * h2.x;
        z = sigmoid_f(acc[j].y + b1.y + b2.y); r.y = z * h1.y + (1.f - z) * h2.y;
        z = sigmoid_f(acc[j].z + b1.z + b2.z); r.z = z * h1.z + (1.f - z) * h2.z;
        z = sigmoid_f(acc[j].w + b1.w + b2.w); r.w = z * h1.w + (1.f - z) * h2.w;
        *(float4*)&out[row * 64 + cg * 4] = r;
    }
}

extern "C" void kernel_launch(void* const* d_in, const int* in_sizes, int n_in,
                              void* d_out, int out_size, void* d_ws, size_t ws_size,
                              hipStream_t stream) {
    const float* X    = (const float*)d_in[0];
    const float* STE  = (const float*)d_in[1];
    const float* adp  = (const float*)d_in[2];
    const int*   adj0 = (const int*)d_in[3];
    const int*   adj1 = (const int*)d_in[4];
    const float* w30  = (const float*)d_in[5];
    const float* b30  = (const float*)d_in[6];
    const float* wg   = (const float*)d_in[7];
    const float* bg   = (const float*)d_in[8];
    const float* wg1  = (const float*)d_in[9];   const float* bg1 = (const float*)d_in[10];
    const float* nv1_1= (const float*)d_in[11];  const float* nv2_1 = (const float*)d_in[12];
    const float* wg2  = (const float*)d_in[13];  const float* bg2 = (const float*)d_in[14];
    const float* nv1_2= (const float*)d_in[15];  const float* nv2_2 = (const float*)d_in[16];
    const float* wg3  = (const float*)d_in[17];  const float* bg3 = (const float*)d_in[18];
    const float* nv1_3= (const float*)d_in[19];  const float* nv2_3 = (const float*)d_in[20];
    const float* wg4  = (const float*)d_in[21];  const float* bg4 = (const float*)d_in[22];
    const float* nv1_4= (const float*)d_in[23];  const float* nv2_4 = (const float*)d_in[24];
    const float* w12  = (const float*)d_in[25];  const float* b12 = (const float*)d_in[26];
    const float* w13  = (const float*)d_in[27];  const float* b13 = (const float*)d_in[28];
    const float* w14  = (const float*)d_in[29];  const float* b14 = (const float*)d_in[30];
    const float* w15  = (const float*)d_in[31];  const float* b15 = (const float*)d_in[32];
    const float* w16  = (const float*)d_in[33];  const float* b16 = (const float*)d_in[34];
    const float* w17  = (const float*)d_in[35];  const float* b17 = (const float*)d_in[36];
    const float* w18  = (const float*)d_in[37];  const float* b18 = (const float*)d_in[38];
    const float* w19  = (const float*)d_in[39];  const float* b19 = (const float*)d_in[40];
    const float* w20  = (const float*)d_in[41];  const float* b20 = (const float*)d_in[42];

    // ---- workspace layout ----
    const size_t P_BYTES = 50331648;   // 2*HPK planes (also covers T f32)
    const size_t Q_BYTES = 49152000;   // H1 f32
    const size_t S_BYTES = 6064384;    // A f32 + Apk  /  ApkT hi+lo
    const size_t need = P_BYTES + Q_BYTES + S_BYTES;   // 105,548,032
    if (ws_size < need) return;

    char* wsb = (char*)d_ws;
    ushort_t* Hpk  = (ushort_t*)wsb;                       // hi plane; lo at +HPK_ELEMS
    float*    T    = (float*)wsb;                          // attn-phase overlay
    float*    H1   = (float*)(wsb + P_BYTES);
    char*     S    = wsb + P_BYTES + Q_BYTES;
    float*    A    = (float*)S;                            // gat phase
    ushort_t* Apk  = (ushort_t*)(S + 4000000);             // gat phase
    ushort_t* ApkT = (ushort_t*)S;                         // gcn phase (hi; lo at +APK_ELEMS)
    float*    OUT  = (float*)d_out;                        // HS accumulator

    const dim3 aggGrid(16, BT);
    const int linGrid = BTN / ROWS_PER_BLK;   // 3000
    const int packGrid = (63 * 32 * 64 + 255) / 256;  // 504

    Srcs s{}; Wts w{};
    const int WCH = 64 * 64;

    // zero both Hpk planes (pad K-slots must read 0; ws is poisoned each run)
    hipMemsetAsync(Hpk, 0, P_BYTES, stream);

    // ---- HS accumulator init: OUT = X @ w30[0:64] ----
    s.p[0] = X; w.p[0] = w30;
    lin_kernel<false, false, false, false, 0><<<linGrid, 256, 0, stream>>>(s, w, 1, nullptr, nullptr, OUT);

    // ---- gat1 ----
    adp_softmax_kernel<<<NN, 256, 0, stream>>>(nv1_1, nv2_1, adj0, A);
    pack_adj_kernel<false, false><<<packGrid, 256, 0, stream>>>(A, Apk, Apk);
    s.p[0] = X; s.p[1] = STE; w.p[0] = wg1; w.p[1] = wg1 + WCH;
    lin_kernel<false, true, true, false, 1><<<linGrid, 256, 0, stream>>>(s, w, 2, bg1, nullptr, (float*)Hpk);
    agg_mfma_kernel<true, false><<<aggGrid, 256, 0, stream>>>(Apk, Hpk, H1);
    s.p[0] = H1; w.p[0] = w30 + 1 * WCH;
    lin_kernel<true, false, false, false, 0><<<linGrid, 256, 0, stream>>>(s, w, 1, nullptr, nullptr, OUT);

    // ---- gat2 ----
    s.p[0] = H1; s.p[1] = STE; w.p[0] = wg2; w.p[1] = wg2 + WCH;
    lin_kernel<false, true, true, false, 1><<<linGrid, 256, 0, stream>>>(s, w, 2, bg2, nullptr, (float*)Hpk);
    adp_softmax_kernel<<<NN, 256, 0, stream>>>(nv1_2, nv2_2, adj0, A);
    pack_adj_kernel<false, false><<<packGrid, 256, 0, stream>>>(A, Apk, Apk);
    agg_mfma_kernel<true, false><<<aggGrid, 256, 0, stream>>>(Apk, Hpk, H1);
    s.p[0] = H1; w.p[0] = w30 + 2 * WCH;
    lin_kernel<true, false, false, false, 0><<<linGrid, 256, 0, stream>>>(s, w, 1, nullptr, nullptr, OUT);

    // ---- gat3 ----
    adp_softmax_kernel<<<NN, 256, 0, stream>>>(nv1_3, nv2_3, adj1, A);
    pack_adj_kernel<false, false><<<packGrid, 256, 0, stream>>>(A, Apk, Apk);
    s.p[0] = X; s.p[1] = STE; w.p[0] = wg3; w.p[1] = wg3 + WCH;
    lin_kernel<false, true, true, false, 1><<<linGrid, 256, 0, stream>>>(s, w, 2, bg3, nullptr, (float*)Hpk);
    agg_mfma_kernel<true, false><<<aggGrid, 256, 0, stream>>>(Apk, Hpk, H1);
    s.p[0] = H1; w.p[0] = w30 + 3 * WCH;
    lin_kernel<true, false, false, false, 0><<<linGrid, 256, 0, stream>>>(s, w, 1, nullptr, nullptr, OUT);

    // ---- gat4 ----
    s.p[0] = H1; s.p[1] = STE; w.p[0] = wg4; w.p[1] = wg4 + WCH;
    lin_kernel<false, true, true, false, 1><<<linGrid, 256, 0, stream>>>(s, w, 2, bg4, nullptr, (float*)Hpk);
    adp_softmax_kernel<<<NN, 256, 0, stream>>>(nv1_4, nv2_4, adj1, A);
    pack_adj_kernel<false, false><<<packGrid, 256, 0, stream>>>(A, Apk, Apk);
    agg_mfma_kernel<true, false><<<aggGrid, 256, 0, stream>>>(Apk, Hpk, H1);
    s.p[0] = H1; w.p[0] = w30 + 4 * WCH;
    lin_kernel<true, false, false, false, 0><<<linGrid, 256, 0, stream>>>(s, w, 1, nullptr, nullptr, OUT);

    // ---- pack adp^T split (A/Apk now dead; overlay them) ----
    pack_adj_kernel<true, true><<<packGrid, 256, 0, stream>>>(adp, ApkT, ApkT + APK_ELEMS);

    // ---- gcn5 (split precision, no outer gelu) ----
    s.p[0] = X; s.p[1] = STE; w.p[0] = wg; w.p[1] = wg + WCH;
    lin_kernel<false, true, true, false, 2><<<linGrid, 256, 0, stream>>>(s, w, 2, bg, nullptr, (float*)Hpk);
    agg_mfma_kernel<false, true><<<aggGrid, 256, 0, stream>>>(ApkT, Hpk, H1);
    s.p[0] = H1; w.p[0] = w30 + 5 * WCH;
    lin_kernel<true, false, false, false, 0><<<linGrid, 256, 0, stream>>>(s, w, 1, nullptr, nullptr, OUT);

    // ---- gcn6 + finalize HS = gelu(acc + b30) ----
    s.p[0] = H1; s.p[1] = STE; w.p[0] = wg; w.p[1] = wg + WCH;
    lin_kernel<false, true, true, false, 2><<<linGrid, 256, 0, stream>>>(s, w, 2, bg, nullptr, (float*)Hpk);
    agg_mfma_kernel<false, true><<<aggGrid, 256, 0, stream>>>(ApkT, Hpk, H1);
    s.p[0] = H1; w.p[0] = w30 + 6 * WCH;
    lin_kernel<true, true, true, false, 0><<<linGrid, 256, 0, stream>>>(s, w, 1, b30, nullptr, OUT); // OUT = HS

    // ---- temporal attention (P region now free -> T) ----
    attn_fused_kernel<<<dim3(NN, 16), 256, 0, stream>>>(X, STE, w12, b12, w13, b13, w14, b14, T);
    s.p[0] = T; w.p[0] = w15;
    lin_kernel<false, true, true, false, 0><<<linGrid, 256, 0, stream>>>(s, w, 1, b15, nullptr, H1);
    s.p[0] = H1; w.p[0] = w16;
    lin_kernel<false, true, false, false, 0><<<linGrid, 256, 0, stream>>>(s, w, 1, b16, nullptr, T); // T = HT

    // ---- gated fusion ----
    zfuse_kernel<<<linGrid, 256, 0, stream>>>(OUT, T, w17, b17, w18, b18, H1);   // H1 = h
    s.p[0] = H1; w.p[0] = w19;
    lin_kernel<false, true, true, false, 0><<<linGrid, 256, 0, stream>>>(s, w, 1, b19, nullptr, T);
    s.p[0] = T; w.p[0] = w20;
    lin_kernel<false, true, false, true, 0><<<linGrid, 256, 0, stream>>>(s, w, 1, b20, X, OUT); // X + lin
}